// Round 11
// baseline (131.216 us; speedup 1.0000x reference)
//
#include <hip/hip_runtime.h>
#include <math.h>

// Problem shape (fixed by setup_inputs): B=8192 rows, D=2048 cols, fp32.
static constexpr int Dn = 2048;
static constexpr int Bn = 8192;
static constexpr int NBLK  = 512;        // 256 thr each -> 2048 waves
static constexpr int NWAVE = NBLK * 4;   // 4 rows per wave

typedef float f4 __attribute__((ext_vector_type(4)));

__device__ __forceinline__ float dot4(f4 a, f4 b) {
    return a.x * b.x + a.y * b.y + a.z * b.z + a.w * b.w;
}

// 4 rows/wave retry of R4, un-confounded: R4 predated the two key findings
// (R6/R9: allocator sinks batched loads to ~52-64 VGPR without pressure;
// R10: sched_barrier(0) pins the batch and won best-so-far). Structure:
//   batch A: pin {av[8], x0[8], x1[8]} (24 f4 live, fits the 128-reg cap)
//   -> dots A -> issue batch B {x2[8], x3[8]} so it flies under A's
//   butterflies -> pin -> butterflies A -> dots B -> butterflies B.
// Anchor setup amortizes over 4 rows (L2 anchor traffic halves), 512-block
// ramp/tail shrinks, VALU (~5% busy) absorbs the extra dots for free.
// (Last-block fusion: +25 us twice (R6/R9), structurally rejected.)
__global__ __launch_bounds__(256, 4) void k_main(const float* __restrict__ embed,
                                                 const float* __restrict__ ee,
                                                 const float* __restrict__ labels,
                                                 double* __restrict__ part) {
    __shared__ double bE[4], bL[4], bN[4];
    const int t    = threadIdx.x;
    const int lane = t & 63;
    const int w    = t >> 6;
    const int wv   = ((int)blockIdx.x << 2) | w;  // global wave id
    const int j0 = wv, j1 = wv + NWAVE, j2 = wv + 2 * NWAVE, j3 = wv + 3 * NWAVE;

    const f4* r0 = reinterpret_cast<const f4*>(ee + (size_t)j0 * Dn);
    const f4* r1 = reinterpret_cast<const f4*>(ee + (size_t)j1 * Dn);
    const f4* r2 = reinterpret_cast<const f4*>(ee + (size_t)j2 * Dn);
    const f4* r3 = reinterpret_cast<const f4*>(ee + (size_t)j3 * Dn);
    const f4* e0 = reinterpret_cast<const f4*>(embed);

    // ---- batch A: anchor + rows 0,1 (24 dwordx4 in flight per lane) ----
    f4 av[8], x0[8], x1[8];
#pragma unroll
    for (int s = 0; s < 8; ++s) x0[s] = r0[(s << 6) + lane];
#pragma unroll
    for (int s = 0; s < 8; ++s) x1[s] = r1[(s << 6) + lane];
#pragma unroll
    for (int s = 0; s < 8; ++s) av[s] = e0[(s << 6) + lane];

    float lb0 = 0.f, lb1 = 0.f, lb2 = 0.f, lb3 = 0.f;
    if (lane == 0) {
        lb0 = labels[j0]; lb1 = labels[j1]; lb2 = labels[j2]; lb3 = labels[j3];
    }
    __builtin_amdgcn_sched_barrier(0);   // pin batch A above this point

    // ---- dots A (raw, unnormalized anchor) ----
    float ss = 0.f, dt0 = 0.f, sr0 = 0.f, dt1 = 0.f, sr1 = 0.f;
#pragma unroll
    for (int s = 0; s < 8; ++s) {
        ss  += dot4(av[s], av[s]);
        dt0 += dot4(x0[s], av[s]);
        sr0 += dot4(x0[s], x0[s]);
        dt1 += dot4(x1[s], av[s]);
        sr1 += dot4(x1[s], x1[s]);
    }

    // ---- batch B issued now: flies under A's butterfly chains ----
    f4 x2[8], x3[8];
#pragma unroll
    for (int s = 0; s < 8; ++s) x2[s] = r2[(s << 6) + lane];
#pragma unroll
    for (int s = 0; s < 8; ++s) x3[s] = r3[(s << 6) + lane];
    __builtin_amdgcn_sched_barrier(0);   // pin batch B above the butterflies

    // ---- butterflies A (5 independent chains, dual-issue) ----
#pragma unroll
    for (int o = 32; o > 0; o >>= 1) {
        ss  += __shfl_xor(ss,  o, 64);
        dt0 += __shfl_xor(dt0, o, 64);
        dt1 += __shfl_xor(dt1, o, 64);
        sr0 += __shfl_xor(sr0, o, 64);
        sr1 += __shfl_xor(sr1, o, 64);
    }

    // ---- dots B + butterflies B (4 independent chains) ----
    float dt2 = 0.f, sr2 = 0.f, dt3 = 0.f, sr3 = 0.f;
#pragma unroll
    for (int s = 0; s < 8; ++s) {
        dt2 += dot4(x2[s], av[s]);
        sr2 += dot4(x2[s], x2[s]);
        dt3 += dot4(x3[s], av[s]);
        sr3 += dot4(x3[s], x3[s]);
    }
#pragma unroll
    for (int o = 32; o > 0; o >>= 1) {
        dt2 += __shfl_xor(dt2, o, 64);
        dt3 += __shfl_xor(dt3, o, 64);
        sr2 += __shfl_xor(sr2, o, 64);
        sr3 += __shfl_xor(sr3, o, 64);
    }

    // ---- wave triple -> LDS ----
    if (lane == 0) {
        const float nrm = sqrtf(ss);
        const float inv = 1.0f / fmaxf(nrm, 1e-12f);      // F.normalize eps
        const float na  = fmaxf(nrm * inv, 1e-6f);        // = max(||a||,1e-6) ~ 1
        const float sc  = -10.0f * inv / na;              // folds 1/T and inv
        double sE = 0.0, sL = 0.0, sN = 0.0;
        if (j0 != 0) {  // mask: exclude j == i == 0 (j0 == 0 only for wave 0)
            const float neg = sc * dt0 / fmaxf(sqrtf(sr0), 1e-6f);
            sE += (double)expf(neg);  sL += (double)lb0;
            sN += (double)lb0 * (double)neg;
        }
        {
            const float neg = sc * dt1 / fmaxf(sqrtf(sr1), 1e-6f);
            sE += (double)expf(neg);  sL += (double)lb1;
            sN += (double)lb1 * (double)neg;
        }
        {
            const float neg = sc * dt2 / fmaxf(sqrtf(sr2), 1e-6f);
            sE += (double)expf(neg);  sL += (double)lb2;
            sN += (double)lb2 * (double)neg;
        }
        {
            const float neg = sc * dt3 / fmaxf(sqrtf(sr3), 1e-6f);
            sE += (double)expf(neg);  sL += (double)lb3;
            sN += (double)lb3 * (double)neg;
        }
        bE[w] = sE; bL[w] = sL; bN[w] = sN;
    }
    __syncthreads();

    // ---- block triple -> global (SoA; 12 KB total) ----
    if (t == 0) {
        part[blockIdx.x]            = bE[0] + bE[1] + bE[2] + bE[3];
        part[NBLK + blockIdx.x]     = bL[0] + bL[1] + bL[2] + bL[3];
        part[2 * NBLK + blockIdx.x] = bN[0] + bN[1] + bN[2] + bN[3];
    }
}

// Finisher: 1 block, fp64 reduce of 512 block-partials (12 KB, L2-hot):
//   E0 = 1e-12 + SE;  C0 = 1e-12 + l0*SL
//   L0 = -(l0/C0) * (SN - log(E0)*SL);  out = L0/B
__global__ __launch_bounds__(256) void k_final(const double* __restrict__ part,
                                               const float* __restrict__ labels,
                                               float* __restrict__ out) {
    __shared__ double rE[4], rL[4], rN[4];
    const int t = threadIdx.x;
    const int lane = t & 63, wave = t >> 6;

    double sE = 0.0, sL = 0.0, sN = 0.0;
    for (int i = t; i < NBLK; i += 256) {
        sE += part[i];
        sL += part[NBLK + i];
        sN += part[2 * NBLK + i];
    }
#pragma unroll
    for (int o = 32; o > 0; o >>= 1) {
        sE += __shfl_down(sE, o, 64);
        sL += __shfl_down(sL, o, 64);
        sN += __shfl_down(sN, o, 64);
    }
    if (lane == 0) { rE[wave] = sE; rL[wave] = sL; rN[wave] = sN; }
    __syncthreads();
    if (t == 0) {
        const double E0 = 1e-12 + rE[0] + rE[1] + rE[2] + rE[3];
        const double S2 = rL[0] + rL[1] + rL[2] + rL[3];
        const double S3 = rN[0] + rN[1] + rN[2] + rN[3];
        const double l0 = (double)labels[0];
        const double C0 = 1e-12 + l0 * S2;
        const double L0 = -(l0 / C0) * (S3 - log(E0) * S2);
        out[0] = (float)(L0 / (double)Bn);
    }
}

extern "C" void kernel_launch(void* const* d_in, const int* in_sizes, int n_in,
                              void* d_out, int out_size, void* d_ws, size_t ws_size,
                              hipStream_t stream) {
    const float* embed  = (const float*)d_in[0];  // [B, D] — only row 0 used
    const float* ee     = (const float*)d_in[1];  // [B, D]
    const float* labels = (const float*)d_in[2];  // [B]
    float* out = (float*)d_out;

    double* part = (double*)d_ws;  // 3 * NBLK doubles = 12 KB, fully overwritten

    k_main<<<NBLK, 256, 0, stream>>>(embed, ee, labels, part);
    k_final<<<1, 256, 0, stream>>>(part, labels, out);
}